// Round 7
// baseline (191.328 us; speedup 1.0000x reference)
//
#include <hip/hip_runtime.h>
#include <hip/hip_bf16.h>
#include <stdint.h>

// BiLevelRoutingAttention (spiking LIF), T=4 B=2 L=8x32x32 C=256, fp32 I/O.
#define NT 4
#define NB 2
#define NW 32   // windows = 2*4*4
#define NS 256  // tokens/window = 4*8*8
#define NC 256
#define NH 8
#define ND 32
#define NK 4    // topk

#define LDP 40  // padded LDS row stride in u16 (80 B)

typedef unsigned int u32;
typedef unsigned short u16;
typedef __attribute__((ext_vector_type(8))) short bf16x8;
typedef __attribute__((ext_vector_type(8))) unsigned short u16x8;
typedef __attribute__((ext_vector_type(4))) float f32x4;

// natural token index: tok = (t*NB+b)*8192 + Lt*1024 + Lh*32 + Lw
// window decomposition: tok = tb*8192 + wofs(w) + sofs(s)
__device__ __forceinline__ int wofs(int w) {
  return (w >> 4) * 4096 + ((w >> 2) & 3) * 256 + (w & 3) * 8;
}
__device__ __forceinline__ int sofs(int s) {
  return ((s >> 6) << 10) + (((s >> 3) & 7) << 5) + (s & 7);
}
// full element offset in x/out (c-contiguous)
__device__ __forceinline__ size_t x_off(int t, int b, int w, int s, int c) {
  return ((size_t)((t * NB + b) * 8192 + wofs(w) + sofs(s))) * NC + c;
}

// fp32 -> bf16 round-to-nearest-even
__device__ __forceinline__ u32 f2bf(float f) {
  union { float f; u32 i; } u; u.f = f;
  return (u.i + 0x7FFFu + ((u.i >> 16) & 1u)) >> 16;
}

// K1: w_qkv [256][768] fp32 -> Bt [768][256] bf16 (transposed)
__global__ __launch_bounds__(256) void k_convw(const float* __restrict__ w_qkv,
                                               u16* __restrict__ bt) {
  int i = blockIdx.x * 256 + threadIdx.x;
  int k = i / 768, n = i % 768;
  bt[(size_t)n * 256 + k] = (u16)f2bf(w_qkv[i]);
}

// K2: MFMA GEMM in NATURAL token order: qkv[65536][768] = x @ w_qkv + b_qkv,
// spike bits (>=2.0) packed per token; fused region partials (n==0 blocks);
// per-window any-spike flags. 128x128 tile, BK=32 dbuf, 4 waves x 4x4 MFMA.
__global__ __launch_bounds__(256) void k_gemm(const float* __restrict__ x,
                                              const u16* __restrict__ bt,
                                              const float* __restrict__ b_qkv,
                                              u32* __restrict__ qb, u32* __restrict__ kb,
                                              u32* __restrict__ vb,
                                              float* __restrict__ partial,
                                              u32* __restrict__ winflag) {
  __shared__ __align__(16) u16 As[2][128 * LDP];
  __shared__ __align__(16) u16 Bs[2][128 * LDP];
  __shared__ u32 pack[128 * 4];
  __shared__ float4 sums4[2][256];
  __shared__ u32 wfl;

  const int tid = threadIdx.x;
  // XCD-chunked m-major: 8 XCDs x 384 blocks; 6 consecutive v share one m-tile.
  const int v = (blockIdx.x & 7) * 384 + (blockIdx.x >> 3);
  const int mt = v / 6, nt = v % 6;
  const int m0 = mt * 128, n0 = nt * 128;
  const int wave = tid >> 6, lane = tid & 63;
  const int wr = wave >> 1, wc = wave & 1;
  const bool doreg = (nt == 0);

  if (tid == 0) wfl = 0;
  for (int i = tid; i < 128 * 4; i += 256) pack[i] = 0;

  const f32x4 vz = {0.f, 0.f, 0.f, 0.f};
  f32x4 acc[4][4];
#pragma unroll
  for (int m = 0; m < 4; ++m)
#pragma unroll
    for (int n = 0; n < 4; ++n) acc[m][n] = vz;

  auto stage = [&](int buf, int ks) {
    const int k0 = ks * 32;
    const int r0 = tid >> 3, c4 = tid & 7;
    float4 sv = {0.f, 0.f, 0.f, 0.f};
#pragma unroll
    for (int p = 0; p < 4; ++p) {
      int row = p * 32 + r0;
      float4 vx = *reinterpret_cast<const float4*>(&x[(size_t)(m0 + row) * NC + k0 + c4 * 4]);
      sv.x += vx.x; sv.y += vx.y; sv.z += vx.z; sv.w += vx.w;
      uint2 bf;
      bf.x = f2bf(vx.x) | (f2bf(vx.y) << 16);
      bf.y = f2bf(vx.z) | (f2bf(vx.w) << 16);
      *reinterpret_cast<uint2*>(&As[buf][row * LDP + c4 * 4]) = bf;
    }
    if (doreg) sums4[ks & 1][tid] = sv;
#pragma unroll
    for (int p = 0; p < 2; ++p) {
      int idx2 = p * 256 + tid;
      int row = idx2 >> 2, ch = idx2 & 3;
      u16x8 vbb = *reinterpret_cast<const u16x8*>(&bt[(size_t)(n0 + row) * 256 + k0 + ch * 8]);
      *reinterpret_cast<u16x8*>(&Bs[buf][row * LDP + ch * 8]) = vbb;
    }
  };

  stage(0, 0);
  __syncthreads();
#pragma unroll
  for (int ks = 0; ks < 8; ++ks) {
    const int buf = ks & 1;
    // region partial reduce for staged step ks (sums4[ks&1] guarded by prior barrier;
    // this iteration's stage writes the OTHER sums4 buffer)
    if (doreg && (tid >> 5) == ks) {
      int local = tid & 31, c4l = local >> 2, comp = local & 3;
      const float* sp = reinterpret_cast<const float*>(&sums4[ks & 1][0]);
#pragma unroll
      for (int ww = 0; ww < 4; ++ww) {
        float s = 0.f;
#pragma unroll
        for (int j = 0; j < 8; ++j) s += sp[((ww * 8 + j) * 8 + c4l) * 4 + comp];
        partial[((size_t)mt * 4 + ww) * NC + tid] = s;  // channel c == tid
      }
    }
    if (ks < 7) stage(buf ^ 1, ks + 1);
    bf16x8 afr[4], bfr[4];
#pragma unroll
    for (int m = 0; m < 4; ++m)
      afr[m] = *reinterpret_cast<const bf16x8*>(
          &As[buf][(wr * 64 + m * 16 + (lane & 15)) * LDP + (lane >> 4) * 8]);
#pragma unroll
    for (int n = 0; n < 4; ++n)
      bfr[n] = *reinterpret_cast<const bf16x8*>(
          &Bs[buf][(wc * 64 + n * 16 + (lane & 15)) * LDP + (lane >> 4) * 8]);
#pragma unroll
    for (int m = 0; m < 4; ++m)
#pragma unroll
      for (int n = 0; n < 4; ++n)
        acc[m][n] = __builtin_amdgcn_mfma_f32_16x16x32_bf16(afr[m], bfr[n], acc[m][n], 0, 0, 0);
    __syncthreads();
  }

  // epilogue: bias + threshold (spikes ~never fire -> predicated atomicOr)
  float bias[4];
#pragma unroll
  for (int n = 0; n < 4; ++n) bias[n] = b_qkv[n0 + wc * 64 + n * 16 + (lane & 15)];
#pragma unroll
  for (int m = 0; m < 4; ++m)
#pragma unroll
    for (int n = 0; n < 4; ++n)
#pragma unroll
      for (int r = 0; r < 4; ++r) {
        float vv = acc[m][n][r] + bias[n];
        if (vv >= 2.0f) {
          int row = wr * 64 + m * 16 + (lane >> 4) * 4 + r;  // C/D: row=(lane>>4)*4+reg
          int colb = wc * 64 + n * 16 + (lane & 15);         //      col=lane&15
          atomicOr(&pack[row * 4 + (colb >> 5)], 1u << (colb & 31));
        }
      }
  __syncthreads();
  u32* dst = (nt < 2) ? qb : (nt < 4) ? kb : vb;
  const int h0 = (nt * 4) & 7;
  u32 anyb = 0;
  for (int i = tid; i < 128 * 4; i += 256) {
    int row = i >> 2, j = i & 3;
    u32 pv = pack[i];
    dst[(size_t)(m0 + row) * NH + h0 + j] = pv;
    if (pv) anyb |= 1u << ((row & 31) >> 3);  // ww class of this token
  }
  if (anyb) atomicOr(&wfl, anyb);
  __syncthreads();
  if (tid == 0 && wfl) {
    int t = mt >> 7, b = (mt >> 6) & 1, Lt = (mt >> 3) & 7, hh = mt & 7;
    int w0 = (Lt >> 2) * 16 + (hh >> 1) * 4;
    u32 bit = (nt < 2) ? 1u : (nt < 4) ? 2u : 4u;
    for (int ww = 0; ww < 4; ++ww)
      if (wfl & (1u << ww))
        atomicOr(&winflag[(t * NB + b) * NW + w0 + ww], bit);
  }
}

// K3: scores + top-4 from fused partials (ties -> lower index)
__global__ __launch_bounds__(256) void k_scores(const float* __restrict__ partial,
                                                int* __restrict__ idx) {
  __shared__ float rs[NW][NC];
  __shared__ float scval[NW];
  int blk = blockIdx.x;  // 64 = b*32 + w
  int b = blk >> 5, w = blk & 31;
  int tid = threadIdx.x;
  for (int i = tid; i < NW * NC; i += 256) {
    int v = i >> 8, c = i & 255;
    int wt = v >> 4, wh = (v >> 2) & 3, ww = v & 3;
    float s = 0.f;
#pragma unroll
    for (int t = 0; t < NT; ++t)
#pragma unroll
      for (int it = 0; it < 4; ++it)
#pragma unroll
        for (int hl = 0; hl < 2; ++hl) {
          int m = ((t * NB + b) * 8 + wt * 4 + it) * 8 + (wh * 2 + hl);
          s += partial[((size_t)m * 4 + ww) * NC + c];
        }
    rs[v][c] = s * (1.0f / 1024.0f);
  }
  __syncthreads();
  int v = tid >> 3, l8 = tid & 7;
  float sum = 0.f;
  const float* a = rs[w];
  const float* bb = rs[v];
#pragma unroll
  for (int j = 0; j < 32; ++j) sum += a[l8 * 32 + j] * bb[l8 * 32 + j];
  sum += __shfl_xor(sum, 1);
  sum += __shfl_xor(sum, 2);
  sum += __shfl_xor(sum, 4);
  if (l8 == 0) scval[v] = sum * 0.17677669529663687f;
  __syncthreads();
  if (tid == 0) {
    float sc[NW];
#pragma unroll
    for (int j = 0; j < NW; ++j) sc[j] = scval[j];
    for (int kk = 0; kk < NK; ++kk) {
      float best = -__builtin_inff(); int bi = 0;
      for (int j = 0; j < NW; ++j)
        if (sc[j] > best) { best = sc[j]; bi = j; }
      idx[(b * NW + w) * NK + kk] = bi;
      sc[bi] = -__builtin_inff();
    }
  }
}

// K4: attention + proj + window reverse. Fast path via window flags.
__global__ __launch_bounds__(256) void k_attn(const u32* __restrict__ qb,
                                              const u32* __restrict__ kb,
                                              const u32* __restrict__ vb,
                                              const int* __restrict__ idx,
                                              const u32* __restrict__ winflag,
                                              const float* __restrict__ w_proj,
                                              const float* __restrict__ b_proj,
                                              float* __restrict__ out) {
  __shared__ u32 qs[NS * NH];
  __shared__ unsigned short kvc[NH * ND * ND];
  __shared__ u32 ksum[NH * ND];
  __shared__ float attnrow[NC];

  int blk = blockIdx.x;  // 256 = t*64 + b*32 + w
  int t = blk >> 6, b = (blk >> 5) & 1, w = blk & 31;
  int tid = threadIdx.x;

  u32 fs = winflag[(t * NB + b) * NW + w];
  int wj[NK];
  u32 fk = 0, fv = 0;
#pragma unroll
  for (int j = 0; j < NK; ++j) {
    wj[j] = idx[(b * NW + w) * NK + j];
    u32 f = winflag[(t * NB + b) * NW + wj[j]];
    fk |= f & 2u; fv |= f & 4u;
  }
  bool skip = !(fs & 1u) || !fk || !fv;

  if (skip) {
    float bp = b_proj[tid];
    for (int s = 0; s < NS; ++s) out[x_off(t, b, w, s, tid)] = bp;
    return;
  }

  // ---- exact integer slow path (only if spikes exist) ----
  int tb = (t * NB + b) * 8192;
  size_t gb[NK];
#pragma unroll
  for (int j = 0; j < NK; ++j) gb[j] = (size_t)(tb + wofs(wj[j])) * NH;
  size_t qbase = (size_t)(tb + wofs(w)) * NH;
  for (int i = tid; i < NS * NH; i += 256)
    qs[i] = qb[qbase + (size_t)sofs(i >> 3) * NH + (i & 7)];
  {
    int h = tid >> 5, d = tid & 31;
    u32 cnt = 0;
    for (int n = 0; n < NK * NS; ++n)
      cnt += (kb[gb[n >> 8] + (size_t)sofs(n & 255) * NH + h] >> d) & 1u;
    ksum[tid] = cnt;
  }
  for (int p = tid; p < NH * ND * ND; p += 256) {
    int h = p >> 10, d = (p >> 5) & 31, e = p & 31;
    u32 cnt = 0;
    for (int n = 0; n < NK * NS; ++n) {
      size_t a = gb[n >> 8] + (size_t)sofs(n & 255) * NH + h;
      cnt += ((kb[a] >> d) & (vb[a] >> e)) & 1u;
    }
    kvc[p] = (unsigned short)cnt;
  }
  __syncthreads();
  int h = tid >> 5, e = tid & 31;
  float bpv = b_proj[tid];
  for (int s = 0; s < NS; ++s) {
    u32 qw = qs[s * NH + h];
    float num = 0.f, den = 0.f;
    for (int d = 0; d < ND; ++d) {
      if ((qw >> d) & 1u) {
        den += (float)ksum[h * ND + d];
        num += (float)kvc[h * ND * ND + d * ND + e];
      }
    }
    attnrow[tid] = num / (den + 1e-6f);
    __syncthreads();
    float acc = bpv;
    for (int c = 0; c < NC; ++c) acc += attnrow[c] * w_proj[c * NC + tid];
    out[x_off(t, b, w, s, tid)] = acc;
    __syncthreads();
  }
}

extern "C" void kernel_launch(void* const* d_in, const int* in_sizes, int n_in,
                              void* d_out, int out_size, void* d_ws, size_t ws_size,
                              hipStream_t stream) {
  const float* x      = (const float*)d_in[0];
  const float* w_qkv  = (const float*)d_in[1];
  const float* b_qkv  = (const float*)d_in[2];
  const float* w_proj = (const float*)d_in[3];
  const float* b_proj = (const float*)d_in[4];
  float* out = (float*)d_out;

  char* ws = (char*)d_ws;
  float* partial = (float*)ws;                    // 2 MB: [512 mt][4 ww][256 c]
  int* idx       = (int*)(ws + 0x200000);         // 1 KB
  u16* bt        = (u16*)(ws + 0x201000);         // 384 KB bf16 [768][256]
  u32* winflag   = (u32*)(ws + 0x280000);         // 1 KB (t,b,w): bit0 q, bit1 k, bit2 v
  u32* qb        = (u32*)(ws + 0x300000);         // 2 MB each, natural token order
  u32* kb        = qb + (size_t)NT * NB * NW * NS * NH;
  u32* vb        = kb + (size_t)NT * NB * NW * NS * NH;

  hipMemsetAsync(winflag, 0, NT * NB * NW * sizeof(u32), stream);
  k_convw<<<768, 256, 0, stream>>>(w_qkv, bt);
  k_gemm<<<3072, 256, 0, stream>>>(x, bt, b_qkv, qb, kb, vb, partial, winflag);
  k_scores<<<NB * NW, 256, 0, stream>>>(partial, idx);
  k_attn<<<NT * NB * NW, 256, 0, stream>>>(qb, kb, vb, idx, winflag, w_proj, b_proj, out);
}

// Round 8
// 81.934 us; speedup vs baseline: 2.3352x; 2.3352x over previous
//
#include <hip/hip_runtime.h>
#include <hip/hip_bf16.h>
#include <stdint.h>

// BiLevelRoutingAttention (spiking LIF), T=4 B=2 L=8x32x32 C=256, fp32 I/O.
#define NT 4
#define NB 2
#define NW 32   // windows = 2*4*4
#define NS 256  // tokens/window = 4*8*8
#define NC 256
#define NH 8
#define ND 32
#define NK 4    // topk

#define LDP 40  // padded LDS row stride in u16 (80 B)

typedef unsigned int u32;
typedef unsigned short u16;
typedef __attribute__((ext_vector_type(8))) short bf16x8;
typedef __attribute__((ext_vector_type(8))) unsigned short u16x8;
typedef __attribute__((ext_vector_type(4))) float f32x4;

// natural token index: tok = (t*NB+b)*8192 + Lt*1024 + Lh*32 + Lw
// window decomposition: tok = tb*8192 + wofs(w) + sofs(s)
__device__ __forceinline__ int wofs(int w) {
  return (w >> 4) * 4096 + ((w >> 2) & 3) * 256 + (w & 3) * 8;
}
__device__ __forceinline__ int sofs(int s) {
  return ((s >> 6) << 10) + (((s >> 3) & 7) << 5) + (s & 7);
}
__device__ __forceinline__ size_t x_off(int t, int b, int w, int s, int c) {
  return ((size_t)((t * NB + b) * 8192 + wofs(w) + sofs(s))) * NC + c;
}

// fp32 -> bf16 round-to-nearest-even
__device__ __forceinline__ u32 f2bf(float f) {
  union { float f; u32 i; } u; u.f = f;
  return (u.i + 0x7FFFu + ((u.i >> 16) & 1u)) >> 16;
}

// K1: w_qkv [256][768] fp32 -> Bt [768][256] bf16 (transposed)
__global__ __launch_bounds__(256) void k_convw(const float* __restrict__ w_qkv,
                                               u16* __restrict__ bt) {
  int i = blockIdx.x * 256 + threadIdx.x;
  int k = i / 768, n = i % 768;
  bt[(size_t)n * 256 + k] = (u16)f2bf(w_qkv[i]);
}

// K2: MFMA GEMM in NATURAL token order: qkv[65536][768] = x @ w_qkv + b_qkv,
// spike bits (>=2.0) packed per token; fused region partials (n==0 blocks);
// per-window any-spike flags. 128x128 tile, BK=32 dbuf, 4 waves x 4x4 MFMA.
__global__ __launch_bounds__(256) void k_gemm(const float* __restrict__ x,
                                              const u16* __restrict__ bt,
                                              const float* __restrict__ b_qkv,
                                              u32* __restrict__ qb, u32* __restrict__ kb,
                                              u32* __restrict__ vb,
                                              float* __restrict__ partial,
                                              u32* __restrict__ winflag) {
  __shared__ __align__(16) u16 As[2][128 * LDP];
  __shared__ __align__(16) u16 Bs[2][128 * LDP];
  __shared__ u32 pack[128 * 4];
  __shared__ float4 sums4[2][256];
  __shared__ u32 wfl;

  const int tid = threadIdx.x;
  // XCD-chunked m-major: 8 XCDs x 384 blocks; 6 consecutive v share one m-tile.
  const int v = (blockIdx.x & 7) * 384 + (blockIdx.x >> 3);
  const int mt = v / 6, nt = v % 6;
  const int m0 = mt * 128, n0 = nt * 128;
  const int wave = tid >> 6, lane = tid & 63;
  const int wr = wave >> 1, wc = wave & 1;
  const bool doreg = (nt == 0);

  if (tid == 0) wfl = 0;
  for (int i = tid; i < 128 * 4; i += 256) pack[i] = 0;

  const f32x4 vz = {0.f, 0.f, 0.f, 0.f};
  f32x4 acc[4][4];
#pragma unroll
  for (int m = 0; m < 4; ++m)
#pragma unroll
    for (int n = 0; n < 4; ++n) acc[m][n] = vz;

  auto stage = [&](int buf, int ks) {
    const int k0 = ks * 32;
    const int r0 = tid >> 3, c4 = tid & 7;
    float4 sv = {0.f, 0.f, 0.f, 0.f};
#pragma unroll
    for (int p = 0; p < 4; ++p) {
      int row = p * 32 + r0;
      float4 vx = *reinterpret_cast<const float4*>(&x[(size_t)(m0 + row) * NC + k0 + c4 * 4]);
      sv.x += vx.x; sv.y += vx.y; sv.z += vx.z; sv.w += vx.w;
      uint2 bf;
      bf.x = f2bf(vx.x) | (f2bf(vx.y) << 16);
      bf.y = f2bf(vx.z) | (f2bf(vx.w) << 16);
      *reinterpret_cast<uint2*>(&As[buf][row * LDP + c4 * 4]) = bf;
    }
    if (doreg) sums4[ks & 1][tid] = sv;
#pragma unroll
    for (int p = 0; p < 2; ++p) {
      int idx2 = p * 256 + tid;
      int row = idx2 >> 2, ch = idx2 & 3;
      u16x8 vbb = *reinterpret_cast<const u16x8*>(&bt[(size_t)(n0 + row) * 256 + k0 + ch * 8]);
      *reinterpret_cast<u16x8*>(&Bs[buf][row * LDP + ch * 8]) = vbb;
    }
  };

  stage(0, 0);
  __syncthreads();
#pragma unroll
  for (int ks = 0; ks < 8; ++ks) {
    const int buf = ks & 1;
    if (doreg && (tid >> 5) == ks) {
      int local = tid & 31, c4l = local >> 2, comp = local & 3;
      const float* sp = reinterpret_cast<const float*>(&sums4[ks & 1][0]);
#pragma unroll
      for (int ww = 0; ww < 4; ++ww) {
        float s = 0.f;
#pragma unroll
        for (int j = 0; j < 8; ++j) s += sp[((ww * 8 + j) * 8 + c4l) * 4 + comp];
        partial[((size_t)mt * 4 + ww) * NC + tid] = s;  // channel c == tid
      }
    }
    if (ks < 7) stage(buf ^ 1, ks + 1);
    bf16x8 afr[4], bfr[4];
#pragma unroll
    for (int m = 0; m < 4; ++m)
      afr[m] = *reinterpret_cast<const bf16x8*>(
          &As[buf][(wr * 64 + m * 16 + (lane & 15)) * LDP + (lane >> 4) * 8]);
#pragma unroll
    for (int n = 0; n < 4; ++n)
      bfr[n] = *reinterpret_cast<const bf16x8*>(
          &Bs[buf][(wc * 64 + n * 16 + (lane & 15)) * LDP + (lane >> 4) * 8]);
#pragma unroll
    for (int m = 0; m < 4; ++m)
#pragma unroll
      for (int n = 0; n < 4; ++n)
        acc[m][n] = __builtin_amdgcn_mfma_f32_16x16x32_bf16(afr[m], bfr[n], acc[m][n], 0, 0, 0);
    __syncthreads();
  }

  // epilogue: bias + threshold (spikes ~never fire -> predicated atomicOr)
  float bias[4];
#pragma unroll
  for (int n = 0; n < 4; ++n) bias[n] = b_qkv[n0 + wc * 64 + n * 16 + (lane & 15)];
#pragma unroll
  for (int m = 0; m < 4; ++m)
#pragma unroll
    for (int n = 0; n < 4; ++n)
#pragma unroll
      for (int r = 0; r < 4; ++r) {
        float vv = acc[m][n][r] + bias[n];
        if (vv >= 2.0f) {
          int row = wr * 64 + m * 16 + (lane >> 4) * 4 + r;  // C/D: row=(lane>>4)*4+reg
          int colb = wc * 64 + n * 16 + (lane & 15);         //      col=lane&15
          atomicOr(&pack[row * 4 + (colb >> 5)], 1u << (colb & 31));
        }
      }
  __syncthreads();
  u32* dst = (nt < 2) ? qb : (nt < 4) ? kb : vb;
  const int h0 = (nt * 4) & 7;
  u32 anyb = 0;
  for (int i = tid; i < 128 * 4; i += 256) {
    int row = i >> 2, j = i & 3;
    u32 pv = pack[i];
    dst[(size_t)(m0 + row) * NH + h0 + j] = pv;
    if (pv) anyb |= 1u << ((row & 31) >> 3);  // ww class of this token
  }
  if (anyb) atomicOr(&wfl, anyb);
  __syncthreads();
  if (tid == 0 && wfl) {
    int t = mt >> 7, b = (mt >> 6) & 1, Lt = (mt >> 3) & 7, hh = mt & 7;
    int w0 = (Lt >> 2) * 16 + (hh >> 1) * 4;
    u32 bit = (nt < 2) ? 1u : (nt < 4) ? 2u : 4u;
    for (int ww = 0; ww < 4; ++ww)
      if (wfl & (1u << ww))
        atomicOr(&winflag[(t * NB + b) * NW + w0 + ww], bit);
  }
}

// K3a: non-redundant region reduce: region[b][v][c] = (1/1024) * sum of 32 partial slices
__global__ __launch_bounds__(256) void k_reduce(const float* __restrict__ partial,
                                                float* __restrict__ region) {
  int blk = blockIdx.x;  // 64 = b*32 + v
  int b = blk >> 5, v = blk & 31;
  int c = threadIdx.x;
  int wt = v >> 4, wh = (v >> 2) & 3, ww = v & 3;
  float s = 0.f;
#pragma unroll
  for (int t = 0; t < NT; ++t)
#pragma unroll
    for (int it = 0; it < 4; ++it)
#pragma unroll
      for (int hl = 0; hl < 2; ++hl) {
        int m = ((t * NB + b) * 8 + wt * 4 + it) * 8 + (wh * 2 + hl);
        s += partial[((size_t)m * 4 + ww) * NC + c];
      }
  region[(size_t)blk * NC + c] = s * (1.0f / 1024.0f);
}

// K3b: scores + top-4 (ties -> lower index, matching jax.lax.top_k)
__global__ __launch_bounds__(256) void k_scores(const float* __restrict__ region,
                                                int* __restrict__ idx) {
  __shared__ float rs[NW][NC];  // 32 KB
  __shared__ float scval[NW];
  int blk = blockIdx.x;  // 64 = b*32 + w
  int b = blk >> 5, w = blk & 31;
  int tid = threadIdx.x;
  for (int i = tid; i < NW * NC; i += 256)
    rs[i >> 8][i & 255] = region[(size_t)b * NW * NC + i];
  __syncthreads();
  int v = tid >> 3, l8 = tid & 7;
  float sum = 0.f;
  const float* a = rs[w];
  const float* bb = rs[v];
#pragma unroll
  for (int j = 0; j < 32; ++j) sum += a[l8 * 32 + j] * bb[l8 * 32 + j];
  sum += __shfl_xor(sum, 1);
  sum += __shfl_xor(sum, 2);
  sum += __shfl_xor(sum, 4);
  if (l8 == 0) scval[v] = sum * 0.17677669529663687f;  // 32^-0.5
  __syncthreads();
  if (tid == 0) {
    float sc[NW];
#pragma unroll
    for (int j = 0; j < NW; ++j) sc[j] = scval[j];
    for (int kk = 0; kk < NK; ++kk) {
      float best = -__builtin_inff(); int bi = 0;
      for (int j = 0; j < NW; ++j)
        if (sc[j] > best) { best = sc[j]; bi = j; }
      idx[(b * NW + w) * NK + kk] = bi;
      sc[bi] = -__builtin_inff();
    }
  }
}

// K4: attention + proj + window reverse. Fast path via window flags.
__global__ __launch_bounds__(256) void k_attn(const u32* __restrict__ qb,
                                              const u32* __restrict__ kb,
                                              const u32* __restrict__ vb,
                                              const int* __restrict__ idx,
                                              const u32* __restrict__ winflag,
                                              const float* __restrict__ w_proj,
                                              const float* __restrict__ b_proj,
                                              float* __restrict__ out) {
  __shared__ u32 qs[NS * NH];
  __shared__ unsigned short kvc[NH * ND * ND];
  __shared__ u32 ksum[NH * ND];
  __shared__ float attnrow[NC];

  int blk = blockIdx.x;  // 256 = t*64 + b*32 + w
  int t = blk >> 6, b = (blk >> 5) & 1, w = blk & 31;
  int tid = threadIdx.x;

  u32 fs = winflag[(t * NB + b) * NW + w];
  int wj[NK];
  u32 fk = 0, fv = 0;
#pragma unroll
  for (int j = 0; j < NK; ++j) {
    wj[j] = idx[(b * NW + w) * NK + j];
    u32 f = winflag[(t * NB + b) * NW + wj[j]];
    fk |= f & 2u; fv |= f & 4u;
  }
  bool skip = !(fs & 1u) || !fk || !fv;

  if (skip) {
    float bp = b_proj[tid];
    for (int s = 0; s < NS; ++s) out[x_off(t, b, w, s, tid)] = bp;
    return;
  }

  // ---- exact integer slow path (only if spikes exist) ----
  int tb = (t * NB + b) * 8192;
  size_t gb[NK];
#pragma unroll
  for (int j = 0; j < NK; ++j) gb[j] = (size_t)(tb + wofs(wj[j])) * NH;
  size_t qbase = (size_t)(tb + wofs(w)) * NH;
  for (int i = tid; i < NS * NH; i += 256)
    qs[i] = qb[qbase + (size_t)sofs(i >> 3) * NH + (i & 7)];
  {
    int h = tid >> 5, d = tid & 31;
    u32 cnt = 0;
    for (int n = 0; n < NK * NS; ++n)
      cnt += (kb[gb[n >> 8] + (size_t)sofs(n & 255) * NH + h] >> d) & 1u;
    ksum[tid] = cnt;
  }
  for (int p = tid; p < NH * ND * ND; p += 256) {
    int h = p >> 10, d = (p >> 5) & 31, e = p & 31;
    u32 cnt = 0;
    for (int n = 0; n < NK * NS; ++n) {
      size_t a = gb[n >> 8] + (size_t)sofs(n & 255) * NH + h;
      cnt += ((kb[a] >> d) & (vb[a] >> e)) & 1u;
    }
    kvc[p] = (unsigned short)cnt;
  }
  __syncthreads();
  int h = tid >> 5, e = tid & 31;
  float bpv = b_proj[tid];
  for (int s = 0; s < NS; ++s) {
    u32 qw = qs[s * NH + h];
    float num = 0.f, den = 0.f;
    for (int d = 0; d < ND; ++d) {
      if ((qw >> d) & 1u) {
        den += (float)ksum[h * ND + d];
        num += (float)kvc[h * ND * ND + d * ND + e];
      }
    }
    attnrow[tid] = num / (den + 1e-6f);
    __syncthreads();
    float acc = bpv;
    for (int c = 0; c < NC; ++c) acc += attnrow[c] * w_proj[c * NC + tid];
    out[x_off(t, b, w, s, tid)] = acc;
    __syncthreads();
  }
}

extern "C" void kernel_launch(void* const* d_in, const int* in_sizes, int n_in,
                              void* d_out, int out_size, void* d_ws, size_t ws_size,
                              hipStream_t stream) {
  const float* x      = (const float*)d_in[0];
  const float* w_qkv  = (const float*)d_in[1];
  const float* b_qkv  = (const float*)d_in[2];
  const float* w_proj = (const float*)d_in[3];
  const float* b_proj = (const float*)d_in[4];
  float* out = (float*)d_out;

  char* ws = (char*)d_ws;
  float* partial = (float*)ws;                    // 2 MB: [512 mt][4 ww][256 c]
  int* idx       = (int*)(ws + 0x200000);         // 1 KB
  u16* bt        = (u16*)(ws + 0x201000);         // 384 KB bf16 [768][256]
  u32* winflag   = (u32*)(ws + 0x280000);         // 1 KB (t,b,w): bit0 q, bit1 k, bit2 v
  float* region  = (float*)(ws + 0x290000);       // 64 KB: [b][v][c]
  u32* qb        = (u32*)(ws + 0x300000);         // 2 MB each, natural token order
  u32* kb        = qb + (size_t)NT * NB * NW * NS * NH;
  u32* vb        = kb + (size_t)NT * NB * NW * NS * NH;

  hipMemsetAsync(winflag, 0, NT * NB * NW * sizeof(u32), stream);
  k_convw<<<768, 256, 0, stream>>>(w_qkv, bt);
  k_gemm<<<3072, 256, 0, stream>>>(x, bt, b_qkv, qb, kb, vb, partial, winflag);
  k_reduce<<<NB * NW, 256, 0, stream>>>(partial, region);
  k_scores<<<NB * NW, 256, 0, stream>>>(region, idx);
  k_attn<<<NT * NB * NW, 256, 0, stream>>>(qb, kb, vb, idx, winflag, w_proj, b_proj, out);
}